// Round 1
// baseline (1323.376 us; speedup 1.0000x reference)
//
#include <hip/hip_runtime.h>
#include <cstddef>

#define NXS 64
#define NUS 32
#define NYS 32
#define NWS 64
#define BBATCH 256
#define TT  2048

// ws float layout (old path, unchanged):
//  [0,     12288)  Wzt (192x64)
//  [12288, 24576)  Wxt (192x64)
//  [24576, 30720)  Wyt (192x32)
// big-path extras:
#define WS_WZT  0
#define WS_WXT  12288
#define WS_WYT  24576
#define WS_WZS  30720      // 128x64  rows: [x(64); w(64)] -> z
#define WS_WXS  38912      // 128x64  rows: [x; w] -> x'
#define WS_WYS  47104      // 128x32  rows: [x; w] -> y
#define WS_ZU1  51200      // 32x64   u_{t-1} -> z   (Wxu @ C2^T Tinv)
#define WS_ZU2  53248      // 32x64   u_t     -> z   (D21^T Tinv)
#define WS_XU   55296      // 32x64   u_{t-1} -> x'
#define WS_YU   57344      // 32x32   u_{t-1} -> y
#define WS_STRM 65536      // streams [b][2080][160]
#define ST_NT   2080
#define ST_PB   (ST_NT * 160)
#define WS_NEED_BYTES ((size_t)(WS_STRM + (size_t)BBATCH * ST_PB) * 4)

typedef float v2f __attribute__((ext_vector_type(2)));

__device__ __forceinline__ float fast_tanh(float x) {
    float e = __expf(2.0f * x);
    return 1.0f - 2.0f * __builtin_amdgcn_rcpf(e + 1.0f);
}

template<int CTRL>
__device__ __forceinline__ float dpp_row_add(float v) {
    int t = __builtin_amdgcn_update_dpp(0, __float_as_int(v), CTRL, 0xF, 0xF, true);
    return v + __int_as_float(t);
}
__device__ __forceinline__ float row_sum16(float v) {
    v = dpp_row_add<0x121>(v);   // row_ror:1
    v = dpp_row_add<0x122>(v);   // row_ror:2
    v = dpp_row_add<0x124>(v);   // row_ror:4
    v = dpp_row_add<0x128>(v);   // row_ror:8
    return v;
}

// barrier that drains only LDS (lgkm), leaving global loads/stores in flight
__device__ __forceinline__ void step_barrier() {
    asm volatile("s_waitcnt lgkmcnt(0)\n\ts_barrier" ::: "memory");
}

// ---------------------------------------------------------------------------
__global__ __launch_bounds__(256) void setup_kernel(const float* __restrict__ Y,
                                                    const float* __restrict__ lam,
                                                    const float* __restrict__ A,
                                                    const float* __restrict__ B1,
                                                    const float* __restrict__ B2,
                                                    const float* __restrict__ C1,
                                                    const float* __restrict__ D11,
                                                    const float* __restrict__ D12,
                                                    const float* __restrict__ C2,
                                                    const float* __restrict__ D21,
                                                    float* __restrict__ ws,
                                                    int big) {
    __shared__ float M[64 * 129];
    __shared__ float rowk[128];
    __shared__ float ck[64];
    __shared__ float WxL[96 * 64];
    __shared__ float WxwL[64 * 64];
    const int tid = threadIdx.x;

    for (int idx = tid; idx < 64 * 64; idx += 256) {
        int r = idx >> 6, c = idx & 63;
        M[r * 129 + c]      = Y[idx];
        M[r * 129 + 64 + c] = (r == c) ? 1.0f : 0.0f;
    }
    __syncthreads();

    for (int k = 0; k < 64; ++k) {
        float dv = 1.0f / M[k * 129 + k];
        if (tid < 128) rowk[tid] = M[k * 129 + tid] * dv;
        if (tid >= 128 && tid < 192) ck[tid - 128] = M[(tid - 128) * 129 + k];
        __syncthreads();
        for (int idx = tid; idx < 64 * 128; idx += 256) {
            int r = idx >> 7, c = idx & 127;
            float cur = M[r * 129 + c];
            M[r * 129 + c] = (r == k) ? rowk[c] : cur - ck[r] * rowk[c];
        }
        __syncthreads();
    }
    // Yinv[m][j] = M[m*129 + 64 + j]

    // phase 2
    for (int idx = tid; idx < 6144; idx += 256) {        // Wx rows 0..95 of Wxt
        int k = idx >> 6, j = idx & 63;
        float s = 0.0f;
        if (k < 64) {
            #pragma unroll 8
            for (int m = 0; m < 64; ++m) s += A[m * 64 + k] * M[m * 129 + 64 + j];
        } else {
            int ku = k - 64;
            #pragma unroll 8
            for (int m = 0; m < 64; ++m) s += B1[m * 32 + ku] * M[m * 129 + 64 + j];
        }
        WxL[idx] = s;
        ws[WS_WXT + idx] = s;
        if (big) {
            if (k < 64) ws[WS_WXS + k * 64 + j] = s;
            else        ws[WS_XU + (k - 64) * 64 + j] = s;
        }
    }
    for (int idx = tid; idx < 4096; idx += 256) {        // Wxw rows 96..159 of Wxt
        int k = idx >> 6, j = idx & 63;
        float s = 0.0f;
        #pragma unroll 8
        for (int m = 0; m < 64; ++m) s += B2[m * 64 + k] * M[m * 129 + 64 + j];
        WxwL[idx] = s;
        ws[WS_WXT + 6144 + idx] = s;
        if (big) ws[WS_WXS + (64 + k) * 64 + j] = s;
    }
    for (int idx = tid; idx < 2048; idx += 256)          // Wxt rows 160..191 = 0
        ws[WS_WXT + 10240 + idx] = 0.0f;
    for (int idx = tid; idx < 2048; idx += 256) {        // Wzu rows 160..191 of Wzt
        int k = idx >> 6, j = idx & 63;
        float v = D21[j * 32 + k] / lam[j];
        ws[WS_WZT + 10240 + idx] = v;
        if (big) ws[WS_ZU2 + k * 64 + j] = v;
    }
    for (int idx = tid; idx < 5120; idx += 256) {        // Wyt rows 0..159
        int k = idx >> 5, j = idx & 31;
        float v = (k < 64) ? C1[j * 64 + k]
                : (k < 96) ? D11[j * 32 + (k - 64)]
                           : D12[j * 64 + (k - 96)];
        ws[WS_WYT + idx] = v;
        if (big) {
            if (k < 64)      ws[WS_WYS + k * 32 + j] = v;
            else if (k < 96) ws[WS_YU + (k - 64) * 32 + j] = v;
            else             ws[WS_WYS + (k - 32) * 32 + j] = v;
        }
    }
    for (int idx = tid; idx < 1024; idx += 256)          // Wyt rows 160..191 = 0
        ws[WS_WYT + 5120 + idx] = 0.0f;
    __syncthreads();

    // phase 3: Wzz, Wwz
    for (int idx = tid; idx < 6144; idx += 256) {
        int k = idx >> 6, j = idx & 63;
        float s = 0.0f;
        #pragma unroll 8
        for (int m = 0; m < 64; ++m) s += WxL[k * 64 + m] * C2[j * 64 + m];
        float v = s / lam[j];
        ws[WS_WZT + idx] = v;
        if (big) {
            if (k < 64) ws[WS_WZS + k * 64 + j] = v;
            else        ws[WS_ZU1 + (k - 64) * 64 + j] = v;
        }
    }
    for (int idx = tid; idx < 4096; idx += 256) {
        int k = idx >> 6, j = idx & 63;
        float s = 0.0f;
        #pragma unroll 8
        for (int m = 0; m < 64; ++m) s += WxwL[k * 64 + m] * C2[j * 64 + m];
        float v = s / lam[j];
        ws[WS_WZT + 6144 + idx] = v;
        if (big) ws[WS_WZS + (64 + k) * 64 + j] = v;
    }
}

// ---------------------------------------------------------------------------
// Stream precompute: strm[b][t][0..159] = [gz(64) | gx(64) | gy(32)]
//   gz[t] = u_{t-1}@Wzu1 + u_t@Wzu2 ; gx[t] = u_{t-1}@Wxu ; gy[t] = u_{t-1}@Wyu
// Entries t in [0, 2049); [2049,2080) is never-read padding. u_{-1}=u_{2048}=0.
__global__ __launch_bounds__(256) void ustream_kernel(const float* __restrict__ xp,
                                                      const float* __restrict__ ws,
                                                      float* __restrict__ strm) {
    const int bx = blockIdx.x;
    const int b  = bx >> 4;
    const int tb = bx & 15;
    const int t0 = tb << 7;             // 128 entries per block
    const int tid = threadIdx.x;
    __shared__ __align__(16) float uL[130][36];   // uL[k][m] = u_{t0-1+k}[m]
    const float* __restrict__ xpb = xp + (size_t)b * (TT * NUS);

    for (int idx = tid; idx < 130 * 8; idx += 256) {
        int k = idx >> 3, q = idx & 7;
        int t = t0 - 1 + k;
        float4 v = make_float4(0.f, 0.f, 0.f, 0.f);
        if (t >= 0 && t < TT) v = ((const float4*)xpb)[t * 8 + q];
        *(float4*)&uL[k][q * 4] = v;
    }
    __syncthreads();
    const int nte = (tb == 15) ? 129 : 128;       // last block also does entry 2048
    float* __restrict__ ob = strm + (size_t)b * ST_PB + (size_t)t0 * 160;

    {   // gz
        const int j = tid & 63;
        float w1[32], w2[32];
        #pragma unroll
        for (int m = 0; m < 32; ++m) {
            w1[m] = ws[WS_ZU1 + m * 64 + j];
            w2[m] = ws[WS_ZU2 + m * 64 + j];
        }
        for (int e = tid >> 6; e < nte; e += 4) {
            float s = 0.f;
            #pragma unroll
            for (int q = 0; q < 8; ++q) {
                float4 ua = *(const float4*)&uL[e][q * 4];
                float4 ub = *(const float4*)&uL[e + 1][q * 4];
                s += ua.x * w1[4*q] + ua.y * w1[4*q+1] + ua.z * w1[4*q+2] + ua.w * w1[4*q+3];
                s += ub.x * w2[4*q] + ub.y * w2[4*q+1] + ub.z * w2[4*q+2] + ub.w * w2[4*q+3];
            }
            ob[(size_t)e * 160 + j] = s;
        }
    }
    {   // gx
        const int j = tid & 63;
        float w1[32];
        #pragma unroll
        for (int m = 0; m < 32; ++m) w1[m] = ws[WS_XU + m * 64 + j];
        for (int e = tid >> 6; e < nte; e += 4) {
            float s = 0.f;
            #pragma unroll
            for (int q = 0; q < 8; ++q) {
                float4 ua = *(const float4*)&uL[e][q * 4];
                s += ua.x * w1[4*q] + ua.y * w1[4*q+1] + ua.z * w1[4*q+2] + ua.w * w1[4*q+3];
            }
            ob[(size_t)e * 160 + 64 + j] = s;
        }
    }
    {   // gy
        const int j = tid & 31;
        float w1[32];
        #pragma unroll
        for (int m = 0; m < 32; ++m) w1[m] = ws[WS_YU + m * 32 + j];
        for (int e = tid >> 5; e < nte; e += 8) {
            float s = 0.f;
            #pragma unroll
            for (int q = 0; q < 8; ++q) {
                float4 ua = *(const float4*)&uL[e][q * 4];
                s += ua.x * w1[4*q] + ua.y * w1[4*q+1] + ua.z * w1[4*q+2] + ua.w * w1[4*q+3];
            }
            ob[(size_t)e * 160 + 128 + j] = s;
        }
    }
}

// ---------------------------------------------------------------------------
// Big-path scan: S' = [x(64); w(64)] ping-pong, streams via 64-step LDS ring.
// Lane p = lane&15 owns 8 of 128 K-dims (2x ds_read_b128, order-swizzled to
// dodge phase bank conflicts; weight rows permuted to match at init).
// Transpose-reduce (quad_perm x2, select, row_ror:4/8) leaves sum j on lanes
// p&3==j -> tanh/stream-add/writes run on 4 lanes in parallel.
__global__ __launch_bounds__(512, 2) void rnn_big_kernel(const float* __restrict__ xp,
                                                         const float* __restrict__ ws,
                                                         float* __restrict__ out) {
    const int b    = blockIdx.x;
    const int tid  = threadIdx.x;
    const int wv   = tid >> 6;
    const int lane = tid & 63;
    const int p    = lane & 15;
    const int o    = lane >> 4;
    const int sw   = (p >> 2) & 1;

    __shared__ __align__(16) float sbuf[2][128];
    __shared__ __align__(16) float sring[64 * 160];

    const float* __restrict__ strm = ws + WS_STRM + (size_t)b * ST_PB;
    const size_t yb    = (size_t)b * (TT * NYS);
    const size_t xoffo = (size_t)BBATCH * TT * NYS;

    // prologue: S'_{-1} = 0 in sbuf[1]; ring entries [0,64)
    if (tid < 32) ((float4*)&sbuf[1][0])[tid] = make_float4(0.f, 0.f, 0.f, 0.f);
    {
        const float4* st4 = (const float4*)strm;
        float4* sr4 = (float4*)sring;
        #pragma unroll
        for (int q = 0; q < 5; ++q) sr4[tid + q * 512] = st4[tid + q * 512];
    }
    __syncthreads();

    const bool q1 = (p & 3) == 1, q2 = (p & 3) == 2, q3 = (p & 3) == 3;

    if (wv < 4) {
        // ===================== Z waves: z -> tanh -> w (+ ring refresh) ====
        const int g   = wv;
        const int rz  = 4 * g + o;
        const int jzb = 4 * rz;
        const int zo  = 4 * rz + (p & 3);          // gz column (in-bounds all lanes)
        v2f wz2[4][4];
        #pragma unroll
        for (int k2 = 0; k2 < 4; ++k2) {
            int row = 8 * p + 2 * ((k2 + 2 * sw) & 3);
            #pragma unroll
            for (int r = 0; r < 4; ++r)
                wz2[k2][r] = (v2f){ ws[WS_WZS + row * 64 + jzb + r],
                                    ws[WS_WZS + (row + 1) * 64 + jzb + r] };
        }
        float4 rg[5];
        #pragma unroll 4
        for (int i = 0; i < TT; ++i) {
            const int rp = (i + 1) & 1, wp = i & 1;
            if ((i & 31) == 0) {                   // issue loads for entries [i+32,i+64)
                const float4* st4 = (const float4*)(strm + (size_t)(i + 32) * 160);
                #pragma unroll
                for (int q = 0; q < 5; ++q) rg[q] = st4[tid + q * 256];
            }
            if ((i & 31) == 16) {                  // land them 16 steps later
                float4* dst = (float4*)&sring[((i + 16) & 63) * 160];
                #pragma unroll
                for (int q = 0; q < 5; ++q) dst[tid + q * 256] = rg[q];
            }
            float gst = sring[(i & 63) * 160 + zo];
            const float4* sb4 = (const float4*)&sbuf[rp][0];
            float4 Ra = sb4[2 * p + sw];
            float4 Rb = sb4[2 * p + 1 - sw];
            v2f av[4];
            av[0] = (v2f){Ra.x, Ra.y}; av[1] = (v2f){Ra.z, Ra.w};
            av[2] = (v2f){Rb.x, Rb.y}; av[3] = (v2f){Rb.z, Rb.w};
            v2f c0 = {0.f, 0.f}, c1 = c0, c2 = c0, c3 = c0;
            #pragma unroll
            for (int k2 = 0; k2 < 4; ++k2) {
                c0 += av[k2] * wz2[k2][0]; c1 += av[k2] * wz2[k2][1];
                c2 += av[k2] * wz2[k2][2]; c3 += av[k2] * wz2[k2][3];
            }
            float h0 = c0.x + c0.y, h1 = c1.x + c1.y, h2 = c2.x + c2.y, h3 = c3.x + c3.y;
            h0 = dpp_row_add<0xB1>(h0); h0 = dpp_row_add<0x4E>(h0);
            h1 = dpp_row_add<0xB1>(h1); h1 = dpp_row_add<0x4E>(h1);
            h2 = dpp_row_add<0xB1>(h2); h2 = dpp_row_add<0x4E>(h2);
            h3 = dpp_row_add<0xB1>(h3); h3 = dpp_row_add<0x4E>(h3);
            float dz = h0;
            dz = q1 ? h1 : dz; dz = q2 ? h2 : dz; dz = q3 ? h3 : dz;
            dz = dpp_row_add<0x124>(dz); dz = dpp_row_add<0x128>(dz);
            float wvv = fast_tanh(dz + gst);
            if (p < 4) sbuf[wp][64 + zo] = wvv;
            step_barrier();
        }
    } else {
        // ===================== X waves: x' and y ===========================
        const int g   = wv - 4;
        const int rx  = 4 * g + o;
        const int jxb = 4 * rx;
        const int jyb = 2 * rx;
        const int xo  = (p < 4) ? (64 + 4 * rx + (p & 3)) : (128 + 2 * rx + (p & 1));
        const int ycol = jyb + (p & 1);
        const bool qy = (p & 1) == 1;
        v2f wx2[4][4], wy2[4][2];
        #pragma unroll
        for (int k2 = 0; k2 < 4; ++k2) {
            int row = 8 * p + 2 * ((k2 + 2 * sw) & 3);
            #pragma unroll
            for (int r = 0; r < 4; ++r)
                wx2[k2][r] = (v2f){ ws[WS_WXS + row * 64 + jxb + r],
                                    ws[WS_WXS + (row + 1) * 64 + jxb + r] };
            wy2[k2][0] = (v2f){ ws[WS_WYS + row * 32 + jyb],
                                ws[WS_WYS + (row + 1) * 32 + jyb] };
            wy2[k2][1] = (v2f){ ws[WS_WYS + row * 32 + jyb + 1],
                                ws[WS_WYS + (row + 1) * 32 + jyb + 1] };
        }

        float ybat[16];

        auto computeX = [&](const float* Sb, float& dx, float& dy) {
            const float4* sb4 = (const float4*)Sb;
            float4 Ra = sb4[2 * p + sw];
            float4 Rb = sb4[2 * p + 1 - sw];
            v2f av[4];
            av[0] = (v2f){Ra.x, Ra.y}; av[1] = (v2f){Ra.z, Ra.w};
            av[2] = (v2f){Rb.x, Rb.y}; av[3] = (v2f){Rb.z, Rb.w};
            v2f c0 = {0.f, 0.f}, c1 = c0, c2 = c0, c3 = c0, d0 = c0, d1 = c0;
            #pragma unroll
            for (int k2 = 0; k2 < 4; ++k2) {
                c0 += av[k2] * wx2[k2][0]; c1 += av[k2] * wx2[k2][1];
                c2 += av[k2] * wx2[k2][2]; c3 += av[k2] * wx2[k2][3];
                d0 += av[k2] * wy2[k2][0]; d1 += av[k2] * wy2[k2][1];
            }
            float h0 = c0.x + c0.y, h1 = c1.x + c1.y, h2 = c2.x + c2.y, h3 = c3.x + c3.y;
            float e0 = d0.x + d0.y, e1 = d1.x + d1.y;
            h0 = dpp_row_add<0xB1>(h0); h0 = dpp_row_add<0x4E>(h0);
            h1 = dpp_row_add<0xB1>(h1); h1 = dpp_row_add<0x4E>(h1);
            h2 = dpp_row_add<0xB1>(h2); h2 = dpp_row_add<0x4E>(h2);
            h3 = dpp_row_add<0xB1>(h3); h3 = dpp_row_add<0x4E>(h3);
            e0 = dpp_row_add<0xB1>(e0); e0 = dpp_row_add<0x4E>(e0);
            e1 = dpp_row_add<0xB1>(e1); e1 = dpp_row_add<0x4E>(e1);
            float dxv = h0;
            dxv = q1 ? h1 : dxv; dxv = q2 ? h2 : dxv; dxv = q3 ? h3 : dxv;
            dxv = dpp_row_add<0x124>(dxv); dxv = dpp_row_add<0x128>(dxv);
            float dyv = qy ? e1 : e0;
            dyv = dpp_row_add<0x124>(dyv); dyv = dpp_row_add<0x128>(dyv);
            dx = dxv; dy = dyv;
        };

        #pragma unroll 16
        for (int i = 0; i < TT; ++i) {
            const int rp = (i + 1) & 1, wp = i & 1;
            float gst = sring[(i & 63) * 160 + xo];
            float dx, dy;
            computeX(&sbuf[rp][0], dx, dy);
            if (p < 4) sbuf[wp][jxb + (p & 3)] = dx + gst;
            ybat[(i + 15) & 15] = dy + gst;               // y_{i-1}
            if ((i & 15) == 0 && i >= 16 && p >= 4 && p < 6) {
                size_t base = yb + (size_t)(i - 16) * NYS + ycol;
                #pragma unroll
                for (int s = 0; s < 16; ++s) out[base + (size_t)s * NYS] = ybat[s];
            }
            step_barrier();
        }

        // epilogue: y_2047 + x_final from S'_2047 (sbuf[1]); stream entry 2048
        {
            float gst = sring[xo];                        // slot 0 holds entry 2048
            float dx, dy;
            computeX(&sbuf[1][0], dx, dy);
            if (p < 4) out[xoffo + (size_t)b * 64 + jxb + (p & 3)] = dx + gst;
            ybat[15] = dy + gst;
            if (p >= 4 && p < 6) {
                size_t base = yb + (size_t)(TT - 16) * NYS + ycol;
                #pragma unroll
                for (int s = 0; s < 16; ++s) out[base + (size_t)s * NYS] = ybat[s];
            }
        }
    }
}

// ---------------------------------------------------------------------------
// Fallback scan (verbatim previous verified kernel).
__global__ __launch_bounds__(512, 2) void rnn_kernel(const float* __restrict__ xp,
                                                     const float* __restrict__ ws,
                                                     float* __restrict__ out) {
    const int b    = blockIdx.x;
    const int tid  = threadIdx.x;
    const int wv   = tid >> 6;
    const int lane = tid & 63;
    const int p    = lane & 15;
    const int o    = lane >> 4;

    __shared__ __align__(16) float sbuf[2][192];
    __shared__ __align__(16) float uring[2][2048];

    const float* __restrict__ Wzt = ws + WS_WZT;
    const float* __restrict__ Wxt = ws + WS_WXT;
    const float* __restrict__ Wyt = ws + WS_WYT;

    const float4* __restrict__ xp4 = (const float4*)(xp + (size_t)b * (TT * NUS));
    float4* ur4 = (float4*)uring;
    const size_t yb   = (size_t)b * (TT * NYS);
    const size_t xoff = (size_t)BBATCH * TT * NYS;

    if (tid < 40)              ((float4*)&sbuf[1][0])[tid] = make_float4(0.f, 0.f, 0.f, 0.f);
    else if (tid < 48)         ((float4*)&sbuf[1][160])[tid - 40] = xp4[tid - 40];
    ur4[tid] = xp4[tid];
    __syncthreads();

    if (wv < 4) {
        const int g   = wv;
        const int rz  = 4 * g + o;
        const int jzb = 4 * rz;
        v2f wz2[6][4];
        #pragma unroll
        for (int k2 = 0; k2 < 6; ++k2) {
            int row = 12 * p + 2 * k2;
            #pragma unroll
            for (int r = 0; r < 4; ++r)
                wz2[k2][r] = (v2f){ Wzt[row * 64 + jzb + r], Wzt[(row + 1) * 64 + jzb + r] };
        }

        float4 ureg[8];

        #pragma unroll 4
        for (int i = 0; i < TT; ++i) {
            const int rp = (i + 1) & 1, wp = i & 1;

            if (g == 2) {
                if ((i & 63) == 0 && i + 64 < TT) {
                    #pragma unroll
                    for (int q = 0; q < 8; ++q)
                        ureg[q] = xp4[(i + 64) * 8 + q * 64 + lane];
                }
                if ((i & 63) == 32 && i + 96 <= TT) {
                    int nb = ((i >> 6) + 1) & 1;
                    #pragma unroll
                    for (int q = 0; q < 8; ++q)
                        ur4[nb * 512 + q * 64 + lane] = ureg[q];
                }
            }

            const float4* sb4 = (const float4*)&sbuf[rp][0];
            float4 A0 = sb4[3 * p], A1 = sb4[3 * p + 1], A2 = sb4[3 * p + 2];
            v2f av[6];
            av[0] = (v2f){A0.x, A0.y}; av[1] = (v2f){A0.z, A0.w};
            av[2] = (v2f){A1.x, A1.y}; av[3] = (v2f){A1.z, A1.w};
            av[4] = (v2f){A2.x, A2.y}; av[5] = (v2f){A2.z, A2.w};

            v2f c0 = {0.f, 0.f}, c1 = c0, c2 = c0, c3 = c0;
            #pragma unroll
            for (int k2 = 0; k2 < 6; ++k2) {
                c0 += av[k2] * wz2[k2][0]; c1 += av[k2] * wz2[k2][1];
                c2 += av[k2] * wz2[k2][2]; c3 += av[k2] * wz2[k2][3];
            }
            float s0 = row_sum16(c0.x + c0.y);
            float s1 = row_sum16(c1.x + c1.y);
            float s2 = row_sum16(c2.x + c2.y);
            float s3 = row_sum16(c3.x + c3.y);
            if (p == 0)
                ((float4*)&sbuf[wp][96])[rz] =
                    make_float4(fast_tanh(s0), fast_tanh(s1), fast_tanh(s2), fast_tanh(s3));

            if (g == 0 && lane < 8)
                ((float4*)&sbuf[wp][64])[lane] = ((const float4*)&sbuf[rp][160])[lane];
            if (g == 1 && lane < 8) {
                int s = i + 1;
                int cb = (s >> 6) & 1;
                ((float4*)&sbuf[wp][160])[lane] = ur4[cb * 512 + (s & 63) * 8 + lane];
            }
            __syncthreads();
        }
    } else {
        const int g   = wv - 4;
        const int rx  = 4 * g + o;
        const int jxb = 4 * rx;
        const int jyb = 2 * rx;
        v2f wx2[6][4], wy2[6][2];
        #pragma unroll
        for (int k2 = 0; k2 < 6; ++k2) {
            int row = 12 * p + 2 * k2;
            #pragma unroll
            for (int r = 0; r < 4; ++r)
                wx2[k2][r] = (v2f){ Wxt[row * 64 + jxb + r], Wxt[(row + 1) * 64 + jxb + r] };
            wy2[k2][0] = (v2f){ Wyt[row * 32 + jyb],     Wyt[(row + 1) * 32 + jyb] };
            wy2[k2][1] = (v2f){ Wyt[row * 32 + jyb + 1], Wyt[(row + 1) * 32 + jyb + 1] };
        }

        float2 ybat[16];

        auto compute = [&](const float* S, float& sx0, float& sx1, float& sx2,
                           float& sx3, float& sy0, float& sy1) {
            const float4* sb4 = (const float4*)S;
            float4 A0 = sb4[3 * p], A1 = sb4[3 * p + 1], A2 = sb4[3 * p + 2];
            v2f av[6];
            av[0] = (v2f){A0.x, A0.y}; av[1] = (v2f){A0.z, A0.w};
            av[2] = (v2f){A1.x, A1.y}; av[3] = (v2f){A1.z, A1.w};
            av[4] = (v2f){A2.x, A2.y}; av[5] = (v2f){A2.z, A2.w};
            v2f c0 = {0.f, 0.f}, c1 = c0, c2 = c0, c3 = c0, d0 = c0, d1 = c0;
            #pragma unroll
            for (int k2 = 0; k2 < 6; ++k2) {
                c0 += av[k2] * wx2[k2][0]; c1 += av[k2] * wx2[k2][1];
                c2 += av[k2] * wx2[k2][2]; c3 += av[k2] * wx2[k2][3];
                d0 += av[k2] * wy2[k2][0]; d1 += av[k2] * wy2[k2][1];
            }
            sx0 = row_sum16(c0.x + c0.y);
            sx1 = row_sum16(c1.x + c1.y);
            sx2 = row_sum16(c2.x + c2.y);
            sx3 = row_sum16(c3.x + c3.y);
            sy0 = row_sum16(d0.x + d0.y);
            sy1 = row_sum16(d1.x + d1.y);
        };

        #pragma unroll 16
        for (int i = 0; i < TT; ++i) {
            const int rp = (i + 1) & 1, wp = i & 1;
            float sx0, sx1, sx2, sx3, sy0, sy1;
            compute(&sbuf[rp][0], sx0, sx1, sx2, sx3, sy0, sy1);

            if (p == 0)
                ((float4*)&sbuf[wp][0])[rx] = make_float4(sx0, sx1, sx2, sx3);
            ybat[(i + 15) & 15] = make_float2(sy0, sy1);
            if ((i & 15) == 0 && i >= 16 && p == 0) {
                size_t base = yb + (size_t)(i - 16) * NYS + jyb;
                #pragma unroll
                for (int s = 0; s < 16; ++s)
                    *(float2*)&out[base + (size_t)s * NYS] = ybat[s];
            }
            __syncthreads();
        }

        {
            float sx0, sx1, sx2, sx3, sy0, sy1;
            compute(&sbuf[1][0], sx0, sx1, sx2, sx3, sy0, sy1);
            ybat[15] = make_float2(sy0, sy1);
            if (p == 0) {
                *(float4*)&out[xoff + (size_t)b * 64 + jxb] =
                    make_float4(sx0, sx1, sx2, sx3);
                size_t base = yb + (size_t)(TT - 16) * NYS + jyb;
                #pragma unroll
                for (int s = 0; s < 16; ++s)
                    *(float2*)&out[base + (size_t)s * NYS] = ybat[s];
            }
        }
    }
}

// ---------------------------------------------------------------------------
extern "C" void kernel_launch(void* const* d_in, const int* in_sizes, int n_in,
                              void* d_out, int out_size, void* d_ws, size_t ws_size,
                              hipStream_t stream) {
    const float* xp  = (const float*)d_in[0];
    const float* Y   = (const float*)d_in[1];
    const float* lam = (const float*)d_in[2];
    const float* A   = (const float*)d_in[3];
    const float* B1  = (const float*)d_in[4];
    const float* B2  = (const float*)d_in[5];
    const float* C1  = (const float*)d_in[6];
    const float* D11 = (const float*)d_in[7];
    const float* D12 = (const float*)d_in[8];
    const float* C2  = (const float*)d_in[9];
    const float* D21 = (const float*)d_in[10];
    float* out = (float*)d_out;
    float* ws  = (float*)d_ws;

    const int big = (ws_size >= WS_NEED_BYTES) ? 1 : 0;

    hipLaunchKernelGGL(setup_kernel, dim3(1), dim3(256), 0, stream,
                       Y, lam, A, B1, B2, C1, D11, D12, C2, D21, ws, big);
    if (big) {
        hipLaunchKernelGGL(ustream_kernel, dim3(BBATCH * 16), dim3(256), 0, stream,
                           xp, ws, ws + WS_STRM);
        hipLaunchKernelGGL(rnn_big_kernel, dim3(BBATCH), dim3(512), 0, stream,
                           xp, ws, out);
    } else {
        hipLaunchKernelGGL(rnn_kernel, dim3(BBATCH), dim3(512), 0, stream, xp, ws, out);
    }
}

// Round 2
// 1083.295 us; speedup vs baseline: 1.2216x; 1.2216x over previous
//
#include <hip/hip_runtime.h>
#include <cstddef>

#define NXS 64
#define NUS 32
#define NYS 32
#define NWS 64
#define BBATCH 256
#define TT  2048

// ws float layout:
//  [0,     12288)  Wzt (192x64): rows 0..63 x-part, 64..95 u-part, 96..159 w-part, 160..191 u_t-part
//  [12288, 24576)  Wxt (192x64): same row semantics (160..191 zero)
//  [24576, 30720)  Wyt (192x32): same row semantics (160..191 zero)
#define WS_WZT  0
#define WS_WXT  12288
#define WS_WYT  24576

typedef float v2f __attribute__((ext_vector_type(2)));

__device__ __forceinline__ float fast_tanh(float x) {
    float e = __expf(2.0f * x);
    return 1.0f - 2.0f * __builtin_amdgcn_rcpf(e + 1.0f);
}

template<int CTRL>
__device__ __forceinline__ float dpp_row_add(float v) {
    int t = __builtin_amdgcn_update_dpp(0, __float_as_int(v), CTRL, 0xF, 0xF, true);
    return v + __int_as_float(t);
}

// barrier that drains only LDS (lgkm), leaving global loads/stores in flight
__device__ __forceinline__ void step_barrier() {
    asm volatile("s_waitcnt lgkmcnt(0)\n\ts_barrier" ::: "memory");
}

// ---------------------------------------------------------------------------
__global__ __launch_bounds__(1024) void setup_kernel(const float* __restrict__ Y,
                                                     const float* __restrict__ lam,
                                                     const float* __restrict__ A,
                                                     const float* __restrict__ B1,
                                                     const float* __restrict__ B2,
                                                     const float* __restrict__ C1,
                                                     const float* __restrict__ D11,
                                                     const float* __restrict__ D12,
                                                     const float* __restrict__ C2,
                                                     const float* __restrict__ D21,
                                                     float* __restrict__ ws) {
    __shared__ float M[64 * 129];
    __shared__ float rowk[128];
    __shared__ float ck[64];
    __shared__ float WxL[96 * 64];
    __shared__ float WxwL[64 * 64];
    const int tid = threadIdx.x;

    for (int idx = tid; idx < 64 * 64; idx += 1024) {
        int r = idx >> 6, c = idx & 63;
        M[r * 129 + c]      = Y[idx];
        M[r * 129 + 64 + c] = (r == c) ? 1.0f : 0.0f;
    }
    __syncthreads();

    for (int k = 0; k < 64; ++k) {
        float dv = 1.0f / M[k * 129 + k];
        if (tid < 128) rowk[tid] = M[k * 129 + tid] * dv;
        if (tid >= 128 && tid < 192) ck[tid - 128] = M[(tid - 128) * 129 + k];
        __syncthreads();
        for (int idx = tid; idx < 64 * 128; idx += 1024) {
            int r = idx >> 7, c = idx & 127;
            float cur = M[r * 129 + c];
            M[r * 129 + c] = (r == k) ? rowk[c] : cur - ck[r] * rowk[c];
        }
        __syncthreads();
    }
    // Yinv[m][j] = M[m*129 + 64 + j]

    // phase 2
    for (int idx = tid; idx < 6144; idx += 1024) {       // Wx rows 0..95 of Wxt
        int k = idx >> 6, j = idx & 63;
        float s = 0.0f;
        if (k < 64) {
            #pragma unroll 8
            for (int m = 0; m < 64; ++m) s += A[m * 64 + k] * M[m * 129 + 64 + j];
        } else {
            int ku = k - 64;
            #pragma unroll 8
            for (int m = 0; m < 64; ++m) s += B1[m * 32 + ku] * M[m * 129 + 64 + j];
        }
        WxL[idx] = s;
        ws[WS_WXT + idx] = s;
    }
    for (int idx = tid; idx < 4096; idx += 1024) {       // Wxw rows 96..159 of Wxt
        int k = idx >> 6, j = idx & 63;
        float s = 0.0f;
        #pragma unroll 8
        for (int m = 0; m < 64; ++m) s += B2[m * 64 + k] * M[m * 129 + 64 + j];
        WxwL[idx] = s;
        ws[WS_WXT + 6144 + idx] = s;
    }
    for (int idx = tid; idx < 2048; idx += 1024)         // Wxt rows 160..191 = 0
        ws[WS_WXT + 10240 + idx] = 0.0f;
    for (int idx = tid; idx < 2048; idx += 1024) {       // Wzu rows 160..191 of Wzt
        int k = idx >> 6, j = idx & 63;
        ws[WS_WZT + 10240 + idx] = D21[j * 32 + k] / lam[j];
    }
    for (int idx = tid; idx < 5120; idx += 1024) {       // Wyt rows 0..159
        int k = idx >> 5, j = idx & 31;
        float v = (k < 64) ? C1[j * 64 + k]
                : (k < 96) ? D11[j * 32 + (k - 64)]
                           : D12[j * 64 + (k - 96)];
        ws[WS_WYT + idx] = v;
    }
    for (int idx = tid; idx < 1024; idx += 1024)         // Wyt rows 160..191 = 0
        ws[WS_WYT + 5120 + idx] = 0.0f;
    __syncthreads();

    // phase 3: Wzz, Wwz
    for (int idx = tid; idx < 6144; idx += 1024) {
        int k = idx >> 6, j = idx & 63;
        float s = 0.0f;
        #pragma unroll 8
        for (int m = 0; m < 64; ++m) s += WxL[k * 64 + m] * C2[j * 64 + m];
        ws[WS_WZT + idx] = s / lam[j];
    }
    for (int idx = tid; idx < 4096; idx += 1024) {
        int k = idx >> 6, j = idx & 63;
        float s = 0.0f;
        #pragma unroll 8
        for (int m = 0; m < 64; ++m) s += WxwL[k * 64 + m] * C2[j * 64 + m];
        ws[WS_WZT + 6144 + idx] = s / lam[j];
    }
}

// ---------------------------------------------------------------------------
// Scan v2: S' = [x(64); w(64)] ping-pong. u-dependent gains gz/gx/gy computed
// IN-KERNEL (off the serial critical path) into a 16-step double-buffered LDS
// ring: entry e holds [gz_e(64) | gx_e(64) | gy_e(32)] where
//   gz_e = u_{e-1}@ZU1 + u_e@ZU2, gx_e = u_{e-1}@XU, gy_e = u_{e-1}@YU
// (ZU1 = Wzt rows 64..95, ZU2 = rows 160..191, XU = Wxt 64..95, YU = Wyt 64..95).
// Per-lane K: p = lane&15 owns dims [8p,8p+8) (2x ds_read_b128, sw-swizzled).
// Quad-transpose reduce lands col (p&3) sum on every lane; p<4 lanes write.
__global__ __launch_bounds__(512, 2) void rnn2_kernel(const float* __restrict__ xp,
                                                      const float* __restrict__ ws,
                                                      float* __restrict__ out) {
    const int b    = blockIdx.x;
    const int tid  = threadIdx.x;
    const int wv   = tid >> 6;
    const int lane = tid & 63;
    const int p    = lane & 15;
    const int o    = lane >> 4;
    const int sw   = (p >> 2) & 1;

    __shared__ __align__(16) float sbuf[2][128];
    __shared__ __align__(16) float sring[2][16][160];
    __shared__ __align__(16) float uR[32][32];     // u step s -> uR[s&31]

    const float* __restrict__ Wzt = ws + WS_WZT;
    const float* __restrict__ Wxt = ws + WS_WXT;
    const float* __restrict__ Wyt = ws + WS_WYT;

    const float4* __restrict__ xp4 = (const float4*)(xp + (size_t)b * (TT * NUS));
    const size_t yb   = (size_t)b * (TT * NYS);
    const size_t xoff = (size_t)BBATCH * TT * NYS;

    // init: uR slots 0..15 = u_0..15, slot 31 = u_{-1} = 0, sbuf[1] = S'_{-1} = 0
    if (tid < 128) {
        int s = tid >> 3, q = tid & 7;
        *(float4*)&uR[s][q * 4] = xp4[s * 8 + q];
    } else if (tid < 136) {
        *(float4*)&uR[31][(tid - 128) * 4] = make_float4(0.f, 0.f, 0.f, 0.f);
    } else if (tid < 168) {
        ((float4*)&sbuf[1][0])[tid - 136] = make_float4(0.f, 0.f, 0.f, 0.f);
    }
    __syncthreads();

    const bool q1 = (p & 3) == 1, q2 = (p & 3) == 2, q3 = (p & 3) == 3;

    if (wv < 4) {
        // ===================== Z waves: z -> tanh -> w; ring gz ============
        const int g   = wv;
        const int rz  = 4 * g + o;
        const int jzb = 4 * rz;
        const int zo  = jzb + (p & 3);
        v2f wz2[4][4];
        #pragma unroll
        for (int k2 = 0; k2 < 4; ++k2) {
            int row = 8 * p + 2 * ((k2 + 2 * sw) & 3);
            int r0  = row + (row >= 64 ? 32 : 0);          // remap to old layout
            #pragma unroll
            for (int r = 0; r < 4; ++r)
                wz2[k2][r] = (v2f){ Wzt[r0 * 64 + jzb + r], Wzt[(r0 + 1) * 64 + jzb + r] };
        }
        v2f zu1[16], zu2[16];
        #pragma unroll
        for (int mm = 0; mm < 16; ++mm) {
            zu1[mm] = (v2f){ Wzt[(64  + 2 * mm) * 64 + lane], Wzt[(65  + 2 * mm) * 64 + lane] };
            zu2[mm] = (v2f){ Wzt[(160 + 2 * mm) * 64 + lane], Wzt[(161 + 2 * mm) * 64 + lane] };
        }

        float4 ucz[8];
        auto ringZ = [&](int e, bool usecache) {
            const float4* P = (const float4*)uR[(e - 1) & 31];
            const float4* C = (const float4*)uR[e & 31];
            v2f a = (v2f){0.f, 0.f};
            #pragma unroll
            for (int q = 0; q < 8; ++q) {
                float4 up = usecache ? ucz[q] : P[q];
                float4 uc = C[q];
                a += (v2f){up.x, up.y} * zu1[2 * q] + (v2f){up.z, up.w} * zu1[2 * q + 1];
                a += (v2f){uc.x, uc.y} * zu2[2 * q] + (v2f){uc.z, uc.w} * zu2[2 * q + 1];
                ucz[q] = uc;
            }
            sring[(e >> 4) & 1][e & 15][lane] = a.x + a.y;
        };

        #pragma unroll
        for (int j = 0; j < 4; ++j) ringZ(4 * g + j, false);   // ring chunk 0
        __syncthreads();

        float4 ufetch;
        for (int c = 0; c < TT / 16; ++c) {
            #pragma unroll
            for (int off = 0; off < 16; ++off) {
                const int rp = (off + 1) & 1, wp = off & 1;
                if (off == 0 && tid < 128 && c + 1 < TT / 16) {
                    int s = 16 * (c + 1) + (tid >> 3);
                    ufetch = xp4[s * 8 + (tid & 7)];
                }
                if (off == 4 && tid < 128 && c + 1 < TT / 16) {
                    int s = 16 * (c + 1) + (tid >> 3);
                    *(float4*)&uR[s & 31][(tid & 7) * 4] = ufetch;
                }
                if (off == 5 || off == 8 || off == 11 || off == 14)
                    ringZ(16 * (c + 1) + 4 * g + (off - 5) / 3, off != 5);

                const float4* sb4 = (const float4*)&sbuf[rp][0];
                float4 Ra = sb4[2 * p + sw];
                float4 Rb = sb4[2 * p + 1 - sw];
                v2f av[4] = { {Ra.x, Ra.y}, {Ra.z, Ra.w}, {Rb.x, Rb.y}, {Rb.z, Rb.w} };
                v2f c0 = {0.f, 0.f}, c1 = c0, c2 = c0, c3 = c0;
                #pragma unroll
                for (int k2 = 0; k2 < 4; ++k2) {
                    c0 += av[k2] * wz2[k2][0]; c1 += av[k2] * wz2[k2][1];
                    c2 += av[k2] * wz2[k2][2]; c3 += av[k2] * wz2[k2][3];
                }
                float h0 = c0.x + c0.y, h1 = c1.x + c1.y, h2 = c2.x + c2.y, h3 = c3.x + c3.y;
                h0 = dpp_row_add<0xB1>(h0); h0 = dpp_row_add<0x4E>(h0);
                h1 = dpp_row_add<0xB1>(h1); h1 = dpp_row_add<0x4E>(h1);
                h2 = dpp_row_add<0xB1>(h2); h2 = dpp_row_add<0x4E>(h2);
                h3 = dpp_row_add<0xB1>(h3); h3 = dpp_row_add<0x4E>(h3);
                float dz = h0;
                dz = q1 ? h1 : dz; dz = q2 ? h2 : dz; dz = q3 ? h3 : dz;
                dz = dpp_row_add<0x124>(dz); dz = dpp_row_add<0x128>(dz);
                float gst = sring[c & 1][off][zo];
                float wvv = fast_tanh(dz + gst);
                if (p < 4) sbuf[wp][64 + zo] = wvv;
                step_barrier();
            }
        }
    } else {
        // ===================== X waves: x', y; ring gx/gy ==================
        const int g    = wv - 4;
        const int rx   = 4 * g + o;
        const int jxb  = 4 * rx;
        const int jyb  = 2 * rx;
        const int xo   = (p < 4) ? (64 + jxb + (p & 3)) : (128 + jyb + (p & 1));
        const int ycol = jyb + (p & 1);
        const bool qy  = (p & 1) != 0;
        v2f wx2[4][4], wy2[4][2];
        #pragma unroll
        for (int k2 = 0; k2 < 4; ++k2) {
            int row = 8 * p + 2 * ((k2 + 2 * sw) & 3);
            int r0  = row + (row >= 64 ? 32 : 0);
            #pragma unroll
            for (int r = 0; r < 4; ++r)
                wx2[k2][r] = (v2f){ Wxt[r0 * 64 + jxb + r], Wxt[(r0 + 1) * 64 + jxb + r] };
            wy2[k2][0] = (v2f){ Wyt[r0 * 32 + jyb],     Wyt[(r0 + 1) * 32 + jyb] };
            wy2[k2][1] = (v2f){ Wyt[r0 * 32 + jyb + 1], Wyt[(r0 + 1) * 32 + jyb + 1] };
        }
        const int l31 = lane & 31;
        v2f xu[16], yu[16];
        #pragma unroll
        for (int mm = 0; mm < 16; ++mm) {
            xu[mm] = (v2f){ Wxt[(64 + 2 * mm) * 64 + lane], Wxt[(65 + 2 * mm) * 64 + lane] };
            yu[mm] = (v2f){ Wyt[(64 + 2 * mm) * 32 + l31],  Wyt[(65 + 2 * mm) * 32 + l31] };
        }

        auto ringX = [&](int e) {
            const float4* P = (const float4*)uR[(e - 1) & 31];
            v2f ax = (v2f){0.f, 0.f}, ay = ax;
            #pragma unroll
            for (int q = 0; q < 8; ++q) {
                float4 up = P[q];
                v2f u0 = {up.x, up.y}, u1 = {up.z, up.w};
                ax += u0 * xu[2 * q] + u1 * xu[2 * q + 1];
                ay += u0 * yu[2 * q] + u1 * yu[2 * q + 1];
            }
            const int nb = (e >> 4) & 1, sl = e & 15;
            sring[nb][sl][64 + lane] = ax.x + ax.y;
            if (lane < 32) sring[nb][sl][128 + lane] = ay.x + ay.y;
        };

        #pragma unroll
        for (int j = 0; j < 4; ++j) ringX(4 * g + j);      // ring chunk 0
        __syncthreads();

        float ybat[16];

        auto computeX = [&](const float* Sb, float& dxo, float& dyo) {
            const float4* sb4 = (const float4*)Sb;
            float4 Ra = sb4[2 * p + sw];
            float4 Rb = sb4[2 * p + 1 - sw];
            v2f av[4] = { {Ra.x, Ra.y}, {Ra.z, Ra.w}, {Rb.x, Rb.y}, {Rb.z, Rb.w} };
            v2f c0 = {0.f, 0.f}, c1 = c0, c2 = c0, c3 = c0, d0 = c0, d1 = c0;
            #pragma unroll
            for (int k2 = 0; k2 < 4; ++k2) {
                c0 += av[k2] * wx2[k2][0]; c1 += av[k2] * wx2[k2][1];
                c2 += av[k2] * wx2[k2][2]; c3 += av[k2] * wx2[k2][3];
                d0 += av[k2] * wy2[k2][0]; d1 += av[k2] * wy2[k2][1];
            }
            float h0 = c0.x + c0.y, h1 = c1.x + c1.y, h2 = c2.x + c2.y, h3 = c3.x + c3.y;
            float e0 = d0.x + d0.y, e1 = d1.x + d1.y;
            h0 = dpp_row_add<0xB1>(h0); h0 = dpp_row_add<0x4E>(h0);
            h1 = dpp_row_add<0xB1>(h1); h1 = dpp_row_add<0x4E>(h1);
            h2 = dpp_row_add<0xB1>(h2); h2 = dpp_row_add<0x4E>(h2);
            h3 = dpp_row_add<0xB1>(h3); h3 = dpp_row_add<0x4E>(h3);
            e0 = dpp_row_add<0xB1>(e0); e0 = dpp_row_add<0x4E>(e0);
            e1 = dpp_row_add<0xB1>(e1); e1 = dpp_row_add<0x4E>(e1);
            float dx = h0;
            dx = q1 ? h1 : dx; dx = q2 ? h2 : dx; dx = q3 ? h3 : dx;
            dx = dpp_row_add<0x124>(dx); dx = dpp_row_add<0x128>(dx);
            float dy = qy ? e1 : e0;
            dy = dpp_row_add<0x124>(dy); dy = dpp_row_add<0x128>(dy);
            dxo = dx; dyo = dy;
        };

        for (int c = 0; c < TT / 16; ++c) {
            #pragma unroll
            for (int off = 0; off < 16; ++off) {
                const int rp = (off + 1) & 1, wp = off & 1;
                if (off == 6 || off == 9 || off == 12 || off == 15)
                    ringX(16 * (c + 1) + 4 * g + (off - 6) / 3);
                float gst = sring[c & 1][off][xo];
                float dx, dy;
                computeX(&sbuf[rp][0], dx, dy);
                if (p < 4) sbuf[wp][jxb + (p & 3)] = dx + gst;
                ybat[(off + 15) & 15] = dy + gst;          // y_{i-1}
                if (off == 0 && c >= 1 && (p == 4 || p == 5)) {
                    size_t base = yb + (size_t)(16 * c - 16) * NYS + ycol;
                    #pragma unroll
                    for (int s = 0; s < 16; ++s) out[base + (size_t)s * NYS] = ybat[s];
                }
                step_barrier();
            }
        }

        // epilogue: y_2047 + x_final from S'_2047 (sbuf[1]); ring entry 2048 at [0][0]
        {
            float gst = sring[0][0][xo];
            float dx, dy;
            computeX(&sbuf[1][0], dx, dy);
            if (p < 4) out[xoff + (size_t)b * 64 + jxb + (p & 3)] = dx + gst;
            ybat[15] = dy + gst;
            if (p == 4 || p == 5) {
                size_t base = yb + (size_t)(TT - 16) * NYS + ycol;
                #pragma unroll
                for (int s = 0; s < 16; ++s) out[base + (size_t)s * NYS] = ybat[s];
            }
        }
    }
}

// ---------------------------------------------------------------------------
extern "C" void kernel_launch(void* const* d_in, const int* in_sizes, int n_in,
                              void* d_out, int out_size, void* d_ws, size_t ws_size,
                              hipStream_t stream) {
    const float* xp  = (const float*)d_in[0];
    const float* Y   = (const float*)d_in[1];
    const float* lam = (const float*)d_in[2];
    const float* A   = (const float*)d_in[3];
    const float* B1  = (const float*)d_in[4];
    const float* B2  = (const float*)d_in[5];
    const float* C1  = (const float*)d_in[6];
    const float* D11 = (const float*)d_in[7];
    const float* D12 = (const float*)d_in[8];
    const float* C2  = (const float*)d_in[9];
    const float* D21 = (const float*)d_in[10];
    float* out = (float*)d_out;
    float* ws  = (float*)d_ws;

    hipLaunchKernelGGL(setup_kernel, dim3(1), dim3(1024), 0, stream,
                       Y, lam, A, B1, B2, C1, D11, D12, C2, D21, ws);
    hipLaunchKernelGGL(rnn2_kernel, dim3(BBATCH), dim3(512), 0, stream, xp, ws, out);
}